// Round 4
// baseline (2666.254 us; speedup 1.0000x reference)
//
#include <hip/hip_runtime.h>

#define NB 8
#define NN 8192
#define NC 64
#define NS 1024
#define KK 64

typedef unsigned long long u64;

// ---------------------------------------------------------------------------
// Kernel 1: farthest point sampling, float32 exact — PROVEN bit-exact vs the
// reference in Round 1 (output 0 passed; any selection flip would cascade to
// O(0.3) error). One block (1024 threads) per batch; 8 points/thread in f32
// registers. contract(off) forbids FMA re-rounding; numpy sequential op order.
// Argmax first-occurrence via packed u64 (dist_bits<<32)|(8191-p) max.
// ---------------------------------------------------------------------------
__global__ __launch_bounds__(1024) void fps_kernel(
    const float* __restrict__ pos, float* __restrict__ center_out)
{
#pragma clang fp contract(off)
  const int b = blockIdx.x;
  const int t = threadIdx.x;
  const int lane = t & 63;
  const int wid = t >> 6;
  const float* posb = pos + (size_t)b * (NN * 3);

  __shared__ u64 red[16];
  __shared__ float cpos[3];

  float px[8], py[8], pz[8], dist[8];
#pragma unroll
  for (int k = 0; k < 8; ++k) {
    int p = t + (k << 10);
    px[k] = posb[p * 3 + 0];
    py[k] = posb[p * 3 + 1];
    pz[k] = posb[p * 3 + 2];
    dist[k] = 1e10f;
  }
  if (t == 0) { cpos[0] = px[0]; cpos[1] = py[0]; cpos[2] = pz[0]; }
  __syncthreads();

  for (int it = 0; it < NS; ++it) {
    float cx = cpos[0], cy = cpos[1], cz = cpos[2];
    if (t == 0) {
      float* co = center_out + ((size_t)b * NS + it) * 3;
      co[0] = cx; co[1] = cy; co[2] = cz;
    }

    float bestv = -1.0f;
    int bestp = 0;
#pragma unroll
    for (int k = 0; k < 8; ++k) {
      float dx = px[k] - cx;
      float dy = py[k] - cy;
      float dz = pz[k] - cz;
      float d = ((dx * dx) + (dy * dy)) + (dz * dz);  // contract(off): exact order
      float nd = fminf(dist[k], d);
      dist[k] = nd;
      // k ascending => global index ascending, so strict > keeps first occurrence
      if (nd > bestv) { bestv = nd; bestp = t + (k << 10); }
    }

    u64 key = ((u64)__float_as_uint(bestv) << 32) | (unsigned)(8191 - bestp);
#pragma unroll
    for (int off = 32; off; off >>= 1) {
      u64 ok = __shfl_xor(key, off);
      if (ok > key) key = ok;
    }
    if (lane == 0) red[wid] = key;
    __syncthreads();

    u64 kw = red[lane & 15];
#pragma unroll
    for (int off = 8; off; off >>= 1) {
      u64 ok = __shfl_xor(kw, off);
      if (ok > kw) kw = ok;
    }
    int win = 8191 - (int)(unsigned)kw;

    if (t == (win & 1023)) {
      int kk = win >> 10;
      float ox = px[0], oy = py[0], oz = pz[0];
#pragma unroll
      for (int k2 = 1; k2 < 8; ++k2) {
        if (kk == k2) { ox = px[k2]; oy = py[k2]; oz = pz[k2]; }
      }
      cpos[0] = ox; cpos[1] = oy; cpos[2] = oz;
    }
    __syncthreads();
  }
}

// ---------------------------------------------------------------------------
// Kernel 2: radius ball query, float64 decision boundary (hypothesis H_B: the
// np reference promotes to f64 for the distance matrix). One wave per (b,s).
// sqr = (c2 + p2) - 2*dot in f64, numpy op order; threshold 0.2*0.2 in f64.
// Ballot-compaction in index order == mask->sort->take-K->pad-with-first.
// ---------------------------------------------------------------------------
__global__ __launch_bounds__(256) void ball_kernel(
    const float* __restrict__ pos, const float* __restrict__ center_out,
    int* __restrict__ gidx)
{
#pragma clang fp contract(off)
  const double R2D = 0.2 * 0.2;  // f64, matches python radius**2
  int sw = ((blockIdx.x & 7) << 8) | (blockIdx.x >> 3);  // XCD swizzle
  int gw = (sw << 2) | ((int)threadIdx.x >> 6);
  int lane = threadIdx.x & 63;
  int b = gw >> 10;
  int s = gw & 1023;
  const float* posb = pos + (size_t)b * (NN * 3);
  const float* c = center_out + ((size_t)b * NS + s) * 3;
  double cx = (double)c[0], cy = (double)c[1], cz = (double)c[2];
  double cs = ((cx * cx) + (cy * cy)) + (cz * cz);
  int* out = gidx + ((size_t)b * NS + s) * KK;

  int count = 0;
  int first = -1;
  for (int base = 0; base < NN; base += 64) {
    if (count >= KK) break;
    int p = base + lane;
    double x = (double)posb[p * 3 + 0];
    double y = (double)posb[p * 3 + 1];
    double z = (double)posb[p * 3 + 2];
    double ps = ((x * x) + (y * y)) + (z * z);
    double dt = ((cx * x) + (cy * y)) + (cz * z);
    double sqr = (cs + ps) - (2.0 * dt);
    bool inr = !(sqr > R2D);
    u64 m = __ballot(inr);
    if (first < 0 && m) first = base + __builtin_ctzll(m);
    int pre = __popcll(m & ((1ull << lane) - 1ull));
    int slot = count + pre;
    if (inr && slot < KK) out[slot] = p;
    count += (int)__popcll(m);
  }
  if (count < KK) {
    for (int s2 = count + lane; s2 < KK; s2 += 64) out[s2] = first;
  }
}

// ---------------------------------------------------------------------------
// Kernel 3: gather + 3-layer MLP + max-pool (f32, continuous values only;
// ~1e-5 vs an f64 reference, well under the 2e-2 threshold).
// One block (256 thr) per (b,s). Lane = point, quarter q = channel slice.
// ---------------------------------------------------------------------------
__global__ __launch_bounds__(256) void mlp_kernel(
    const float* __restrict__ pos, const float* __restrict__ feat,
    const float* __restrict__ w1, const float* __restrict__ b1,
    const float* __restrict__ w2, const float* __restrict__ b2,
    const float* __restrict__ w3, const float* __restrict__ b3,
    const int* __restrict__ gidx, const float* __restrict__ center_out,
    float* __restrict__ out_feat)
{
  __shared__ float Xs[64][67];
  __shared__ float H1s[64][65];
  __shared__ float H2s[64][65];

  int bid = blockIdx.x;
  int bs = ((bid & 7) << 10) | (bid >> 3);  // XCD swizzle: batch per XCD
  int b = bs >> 10;
  int t = threadIdx.x;
  int p = t & 63;
  int q = t >> 6;

  int g = gidx[(size_t)bs * KK + p];
  const float* fp = feat + ((size_t)b * NN + g) * NC;
#pragma unroll
  for (int i = 0; i < 4; ++i) {
    float4 v = *(const float4*)(fp + q * 16 + i * 4);
    Xs[p][3 + q * 16 + i * 4 + 0] = v.x;
    Xs[p][3 + q * 16 + i * 4 + 1] = v.y;
    Xs[p][3 + q * 16 + i * 4 + 2] = v.z;
    Xs[p][3 + q * 16 + i * 4 + 3] = v.w;
  }
  if (q == 0) {
    const float* c = center_out + (size_t)bs * 3;
    const float* pp = pos + ((size_t)b * NN + g) * 3;
    Xs[p][0] = pp[0] - c[0];
    Xs[p][1] = pp[1] - c[1];
    Xs[p][2] = pp[2] - c[2];
  }
  __syncthreads();

  // ---- layer 1: [64,67] @ [67,64] ----
  {
    int c0 = q * 16;
    float acc[16];
#pragma unroll
    for (int j = 0; j < 16; ++j) acc[j] = b1[c0 + j];
#pragma unroll 4
    for (int k = 0; k < 67; ++k) {
      float xv = Xs[p][k];
      const float4* wr = (const float4*)(w1 + (size_t)k * 64 + c0);
      float4 wa = wr[0], wb = wr[1], wc = wr[2], wd = wr[3];
      acc[0] = fmaf(xv, wa.x, acc[0]);   acc[1] = fmaf(xv, wa.y, acc[1]);
      acc[2] = fmaf(xv, wa.z, acc[2]);   acc[3] = fmaf(xv, wa.w, acc[3]);
      acc[4] = fmaf(xv, wb.x, acc[4]);   acc[5] = fmaf(xv, wb.y, acc[5]);
      acc[6] = fmaf(xv, wb.z, acc[6]);   acc[7] = fmaf(xv, wb.w, acc[7]);
      acc[8] = fmaf(xv, wc.x, acc[8]);   acc[9] = fmaf(xv, wc.y, acc[9]);
      acc[10] = fmaf(xv, wc.z, acc[10]); acc[11] = fmaf(xv, wc.w, acc[11]);
      acc[12] = fmaf(xv, wd.x, acc[12]); acc[13] = fmaf(xv, wd.y, acc[13]);
      acc[14] = fmaf(xv, wd.z, acc[14]); acc[15] = fmaf(xv, wd.w, acc[15]);
    }
#pragma unroll
    for (int j = 0; j < 16; ++j) H1s[p][c0 + j] = fmaxf(acc[j], 0.0f);
  }
  __syncthreads();

  // ---- layer 2: [64,64] @ [64,64] ----
  {
    int c0 = q * 16;
    float acc[16];
#pragma unroll
    for (int j = 0; j < 16; ++j) acc[j] = b2[c0 + j];
#pragma unroll 4
    for (int k = 0; k < 64; ++k) {
      float xv = H1s[p][k];
      const float4* wr = (const float4*)(w2 + (size_t)k * 64 + c0);
      float4 wa = wr[0], wb = wr[1], wc = wr[2], wd = wr[3];
      acc[0] = fmaf(xv, wa.x, acc[0]);   acc[1] = fmaf(xv, wa.y, acc[1]);
      acc[2] = fmaf(xv, wa.z, acc[2]);   acc[3] = fmaf(xv, wa.w, acc[3]);
      acc[4] = fmaf(xv, wb.x, acc[4]);   acc[5] = fmaf(xv, wb.y, acc[5]);
      acc[6] = fmaf(xv, wb.z, acc[6]);   acc[7] = fmaf(xv, wb.w, acc[7]);
      acc[8] = fmaf(xv, wc.x, acc[8]);   acc[9] = fmaf(xv, wc.y, acc[9]);
      acc[10] = fmaf(xv, wc.z, acc[10]); acc[11] = fmaf(xv, wc.w, acc[11]);
      acc[12] = fmaf(xv, wd.x, acc[12]); acc[13] = fmaf(xv, wd.y, acc[13]);
      acc[14] = fmaf(xv, wd.z, acc[14]); acc[15] = fmaf(xv, wd.w, acc[15]);
    }
#pragma unroll
    for (int j = 0; j < 16; ++j) H2s[p][c0 + j] = fmaxf(acc[j], 0.0f);
  }
  __syncthreads();

  // ---- layer 3: [64,64] @ [64,128], then max over the 64 points ----
  {
    int c1 = q * 32;
    float acc[32];
#pragma unroll
    for (int j = 0; j < 32; ++j) acc[j] = b3[c1 + j];
#pragma unroll 2
    for (int k = 0; k < 64; ++k) {
      float xv = H2s[p][k];
      const float4* wr = (const float4*)(w3 + (size_t)k * 128 + c1);
#pragma unroll
      for (int i = 0; i < 8; ++i) {
        float4 w = wr[i];
        acc[i * 4 + 0] = fmaf(xv, w.x, acc[i * 4 + 0]);
        acc[i * 4 + 1] = fmaf(xv, w.y, acc[i * 4 + 1]);
        acc[i * 4 + 2] = fmaf(xv, w.z, acc[i * 4 + 2]);
        acc[i * 4 + 3] = fmaf(xv, w.w, acc[i * 4 + 3]);
      }
    }
    float* o = out_feat + (size_t)bs * 128 + c1;
#pragma unroll
    for (int j = 0; j < 32; ++j) {
      float v = acc[j];
#pragma unroll
      for (int off = 32; off; off >>= 1) v = fmaxf(v, __shfl_xor(v, off));
      v = fmaxf(v, 0.0f);  // relu commutes with max
      if (p == 0) o[j] = v;
    }
  }
}

extern "C" void kernel_launch(void* const* d_in, const int* in_sizes, int n_in,
                              void* d_out, int out_size, void* d_ws, size_t ws_size,
                              hipStream_t stream)
{
  (void)in_sizes; (void)n_in; (void)out_size; (void)ws_size;
  const float* pos = (const float*)d_in[0];
  const float* feat = (const float*)d_in[1];
  const float* w1 = (const float*)d_in[2];
  const float* b1 = (const float*)d_in[3];
  const float* w2 = (const float*)d_in[4];
  const float* b2 = (const float*)d_in[5];
  const float* w3 = (const float*)d_in[6];
  const float* b3 = (const float*)d_in[7];

  float* center_out = (float*)d_out;                      // [8,1024,3]
  float* out_feat = (float*)d_out + (size_t)NB * NS * 3;  // [8,1024,128]
  int* gidx = (int*)d_ws;                                 // [8,1024,64]

  fps_kernel<<<NB, 1024, 0, stream>>>(pos, center_out);
  ball_kernel<<<(NB * NS) / 4, 256, 0, stream>>>(pos, center_out, gidx);
  mlp_kernel<<<NB * NS, 256, 0, stream>>>(pos, feat, w1, b1, w2, b2, w3, b3,
                                          gidx, center_out, out_feat);
}

// Round 6
// 1495.893 us; speedup vs baseline: 1.7824x; 1.7824x over previous
//
#include <hip/hip_runtime.h>

#define NB 8
#define NN 8192
#define NC 64
#define NS 1024
#define KK 64

typedef unsigned long long u64;

// u64 max-combine with a DPP lane permutation (valid for butterfly max since
// max is commutative+idempotent; patterns pair each lane with a partner that
// already holds its group's max). VALU-pipe only — no LDS traffic.
template <int CTRL>
__device__ __forceinline__ u64 dpp_max_step(u64 k) {
  unsigned lo = (unsigned)k, hi = (unsigned)(k >> 32);
  unsigned plo = (unsigned)__builtin_amdgcn_update_dpp(0, (int)lo, CTRL, 0xF, 0xF, true);
  unsigned phi = (unsigned)__builtin_amdgcn_update_dpp(0, (int)hi, CTRL, 0xF, 0xF, true);
  u64 ok = ((u64)phi << 32) | plo;
  return ok > k ? ok : k;
}
#define DPP_XOR1 0xB1   // quad_perm [1,0,3,2]
#define DPP_XOR2 0x4E   // quad_perm [2,3,0,1]
#define DPP_HM   0x141  // row_half_mirror: i -> 7-i within 8 (pairs quads)
#define DPP_MIR  0x140  // row_mirror: i -> 15-i within 16 (pairs 8-groups)

__device__ __forceinline__ u64 swz16_max(u64 k) {  // lane ^= 16 (ds_swizzle BitMode)
  unsigned lo = (unsigned)k, hi = (unsigned)(k >> 32);
  unsigned plo = (unsigned)__builtin_amdgcn_ds_swizzle((int)lo, 0x401F);
  unsigned phi = (unsigned)__builtin_amdgcn_ds_swizzle((int)hi, 0x401F);
  u64 ok = ((u64)phi << 32) | plo;
  return ok > k ? ok : k;
}

// ---------------------------------------------------------------------------
// Kernel 1: farthest point sampling, float32 exact (bit-exact vs ref since R1;
// selection math byte-identical here — only the reduction transport changed,
// still an exact max over the same packed keys).
// v2: 512 thr × 16 pts; DPP butterfly (VALU) + 1 ds_swizzle + 1 shfl_xor(32);
// ONE barrier/iter via parity-double-buffered partials; winner coords
// re-fetched by all threads from global (uniform L1 broadcast) — no 2nd
// barrier, no LDS cpos round-trip.
// ---------------------------------------------------------------------------
__global__ __launch_bounds__(512) void fps_kernel(
    const float* __restrict__ pos, float* __restrict__ center_out)
{
#pragma clang fp contract(off)
  const int b = blockIdx.x;
  const int t = threadIdx.x;
  const int lane = t & 63;
  const int wid = t >> 6;            // 8 waves
  const float* posb = pos + (size_t)b * (NN * 3);

  __shared__ u64 red[2][8];

  float px[16], py[16], pz[16], dist[16];
#pragma unroll
  for (int k = 0; k < 16; ++k) {
    int p = t + (k << 9);
    px[k] = posb[p * 3 + 0];
    py[k] = posb[p * 3 + 1];
    pz[k] = posb[p * 3 + 2];
    dist[k] = 1e10f;
  }
  float cx = posb[0], cy = posb[1], cz = posb[2];  // far_0 = 0

  for (int it = 0; it < NS; ++it) {
    if (t == 0) {
      float* co = center_out + ((size_t)b * NS + it) * 3;
      co[0] = cx; co[1] = cy; co[2] = cz;
    }

    float bestv = -1.0f;
    int bestp = 0;
#pragma unroll
    for (int k = 0; k < 16; ++k) {
      float dx = px[k] - cx;
      float dy = py[k] - cy;
      float dz = pz[k] - cz;
      float d = ((dx * dx) + (dy * dy)) + (dz * dz);  // contract(off): np order
      float nd = fminf(dist[k], d);
      dist[k] = nd;
      // k ascending => global index ascending: strict > keeps first occurrence
      if (nd > bestv) { bestv = nd; bestp = t + (k << 9); }
    }

    // packed key: (dist_bits<<32)|(8191-p) -> max = farthest, ties -> min index
    u64 key = ((u64)__float_as_uint(bestv) << 32) | (unsigned)(8191 - bestp);
    key = dpp_max_step<DPP_XOR1>(key);   // quad max
    key = dpp_max_step<DPP_XOR2>(key);
    key = dpp_max_step<DPP_HM>(key);     // 8-group max
    key = dpp_max_step<DPP_MIR>(key);    // 16-group max
    key = swz16_max(key);                // 32-group max
    {                                    // 64-lane max
      u64 ok = __shfl_xor(key, 32);
      if (ok > key) key = ok;
    }
    if (lane == 0) red[it & 1][wid] = key;
    __syncthreads();  // partials visible; also fences prior iter's reads

    u64 kw = red[it & 1][lane & 7];      // 8 entries replicated 8x across lanes
    kw = dpp_max_step<DPP_XOR1>(kw);
    kw = dpp_max_step<DPP_XOR2>(kw);
    kw = dpp_max_step<DPP_HM>(kw);       // all lanes: global max key
    int win = 8191 - (int)(unsigned)kw;

    // all threads fetch winner coords from global: uniform address, L1 hit
    const float* wp = posb + (size_t)win * 3;
    cx = wp[0]; cy = wp[1]; cz = wp[2];
  }
}

// ---------------------------------------------------------------------------
// Kernel 2: radius ball query, float64 decision boundary (H_B, verified R4).
// One wave per (b,s); ballot-compaction in index order.
// ---------------------------------------------------------------------------
__global__ __launch_bounds__(256) void ball_kernel(
    const float* __restrict__ pos, const float* __restrict__ center_out,
    int* __restrict__ gidx)
{
#pragma clang fp contract(off)
  const double R2D = 0.2 * 0.2;
  int sw = ((blockIdx.x & 7) << 8) | (blockIdx.x >> 3);  // XCD swizzle
  int gw = (sw << 2) | ((int)threadIdx.x >> 6);
  int lane = threadIdx.x & 63;
  int b = gw >> 10;
  int s = gw & 1023;
  const float* posb = pos + (size_t)b * (NN * 3);
  const float* c = center_out + ((size_t)b * NS + s) * 3;
  double cx = (double)c[0], cy = (double)c[1], cz = (double)c[2];
  double cs = ((cx * cx) + (cy * cy)) + (cz * cz);
  int* out = gidx + ((size_t)b * NS + s) * KK;

  int count = 0;
  int first = -1;
  for (int base = 0; base < NN; base += 64) {
    if (count >= KK) break;
    int p = base + lane;
    double x = (double)posb[p * 3 + 0];
    double y = (double)posb[p * 3 + 1];
    double z = (double)posb[p * 3 + 2];
    double ps = ((x * x) + (y * y)) + (z * z);
    double dt = ((cx * x) + (cy * y)) + (cz * z);
    double sqr = (cs + ps) - (2.0 * dt);
    bool inr = !(sqr > R2D);
    u64 m = __ballot(inr);
    if (first < 0 && m) first = base + __builtin_ctzll(m);
    int pre = __popcll(m & ((1ull << lane) - 1ull));
    int slot = count + pre;
    if (inr && slot < KK) out[slot] = p;
    count += (int)__popcll(m);
  }
  if (count < KK) {
    for (int s2 = count + lane; s2 < KK; s2 += 64) out[s2] = first;
  }
}

// ---------------------------------------------------------------------------
// Kernel 3: gather + 3-layer MLP + max-pool (f32). One block per (b,s).
// v2: readfirstlane(q) proves wave-uniformity of weight/bias addressing so
// the compiler emits s_load (SMEM pipe) instead of per-lane vector loads.
// ---------------------------------------------------------------------------
__global__ __launch_bounds__(256) void mlp_kernel(
    const float* __restrict__ pos, const float* __restrict__ feat,
    const float* __restrict__ w1, const float* __restrict__ b1,
    const float* __restrict__ w2, const float* __restrict__ b2,
    const float* __restrict__ w3, const float* __restrict__ b3,
    const int* __restrict__ gidx, const float* __restrict__ center_out,
    float* __restrict__ out_feat)
{
  __shared__ float Xs[64][67];
  __shared__ float H1s[64][65];
  __shared__ float H2s[64][65];

  int bid = blockIdx.x;
  int bs = ((bid & 7) << 10) | (bid >> 3);  // XCD swizzle: batch per XCD
  int b = bs >> 10;
  int t = threadIdx.x;
  int p = t & 63;
  int q = __builtin_amdgcn_readfirstlane(t >> 6);  // wave-uniform -> SGPR

  int g = gidx[(size_t)bs * KK + p];
  const float* fp = feat + ((size_t)b * NN + g) * NC;
#pragma unroll
  for (int i = 0; i < 4; ++i) {
    float4 v = *(const float4*)(fp + q * 16 + i * 4);
    Xs[p][3 + q * 16 + i * 4 + 0] = v.x;
    Xs[p][3 + q * 16 + i * 4 + 1] = v.y;
    Xs[p][3 + q * 16 + i * 4 + 2] = v.z;
    Xs[p][3 + q * 16 + i * 4 + 3] = v.w;
  }
  if (q == 0) {
    const float* c = center_out + (size_t)bs * 3;
    const float* pp = pos + ((size_t)b * NN + g) * 3;
    Xs[p][0] = pp[0] - c[0];
    Xs[p][1] = pp[1] - c[1];
    Xs[p][2] = pp[2] - c[2];
  }
  __syncthreads();

  // ---- layer 1: [64,67] @ [67,64] ----
  {
    int c0 = q * 16;
    float acc[16];
#pragma unroll
    for (int j = 0; j < 16; ++j) acc[j] = b1[c0 + j];
#pragma unroll 4
    for (int k = 0; k < 67; ++k) {
      float xv = Xs[p][k];
      const float4* wr = (const float4*)(w1 + (size_t)k * 64 + c0);
      float4 wa = wr[0], wb = wr[1], wc = wr[2], wd = wr[3];
      acc[0] = fmaf(xv, wa.x, acc[0]);   acc[1] = fmaf(xv, wa.y, acc[1]);
      acc[2] = fmaf(xv, wa.z, acc[2]);   acc[3] = fmaf(xv, wa.w, acc[3]);
      acc[4] = fmaf(xv, wb.x, acc[4]);   acc[5] = fmaf(xv, wb.y, acc[5]);
      acc[6] = fmaf(xv, wb.z, acc[6]);   acc[7] = fmaf(xv, wb.w, acc[7]);
      acc[8] = fmaf(xv, wc.x, acc[8]);   acc[9] = fmaf(xv, wc.y, acc[9]);
      acc[10] = fmaf(xv, wc.z, acc[10]); acc[11] = fmaf(xv, wc.w, acc[11]);
      acc[12] = fmaf(xv, wd.x, acc[12]); acc[13] = fmaf(xv, wd.y, acc[13]);
      acc[14] = fmaf(xv, wd.z, acc[14]); acc[15] = fmaf(xv, wd.w, acc[15]);
    }
#pragma unroll
    for (int j = 0; j < 16; ++j) H1s[p][c0 + j] = fmaxf(acc[j], 0.0f);
  }
  __syncthreads();

  // ---- layer 2: [64,64] @ [64,64] ----
  {
    int c0 = q * 16;
    float acc[16];
#pragma unroll
    for (int j = 0; j < 16; ++j) acc[j] = b2[c0 + j];
#pragma unroll 4
    for (int k = 0; k < 64; ++k) {
      float xv = H1s[p][k];
      const float4* wr = (const float4*)(w2 + (size_t)k * 64 + c0);
      float4 wa = wr[0], wb = wr[1], wc = wr[2], wd = wr[3];
      acc[0] = fmaf(xv, wa.x, acc[0]);   acc[1] = fmaf(xv, wa.y, acc[1]);
      acc[2] = fmaf(xv, wa.z, acc[2]);   acc[3] = fmaf(xv, wa.w, acc[3]);
      acc[4] = fmaf(xv, wb.x, acc[4]);   acc[5] = fmaf(xv, wb.y, acc[5]);
      acc[6] = fmaf(xv, wb.z, acc[6]);   acc[7] = fmaf(xv, wb.w, acc[7]);
      acc[8] = fmaf(xv, wc.x, acc[8]);   acc[9] = fmaf(xv, wc.y, acc[9]);
      acc[10] = fmaf(xv, wc.z, acc[10]); acc[11] = fmaf(xv, wc.w, acc[11]);
      acc[12] = fmaf(xv, wd.x, acc[12]); acc[13] = fmaf(xv, wd.y, acc[13]);
      acc[14] = fmaf(xv, wd.z, acc[14]); acc[15] = fmaf(xv, wd.w, acc[15]);
    }
#pragma unroll
    for (int j = 0; j < 16; ++j) H2s[p][c0 + j] = fmaxf(acc[j], 0.0f);
  }
  __syncthreads();

  // ---- layer 3: [64,64] @ [64,128], then max over the 64 points ----
  {
    int c1 = q * 32;
    float acc[32];
#pragma unroll
    for (int j = 0; j < 32; ++j) acc[j] = b3[c1 + j];
#pragma unroll 2
    for (int k = 0; k < 64; ++k) {
      float xv = H2s[p][k];
      const float4* wr = (const float4*)(w3 + (size_t)k * 128 + c1);
#pragma unroll
      for (int i = 0; i < 8; ++i) {
        float4 w = wr[i];
        acc[i * 4 + 0] = fmaf(xv, w.x, acc[i * 4 + 0]);
        acc[i * 4 + 1] = fmaf(xv, w.y, acc[i * 4 + 1]);
        acc[i * 4 + 2] = fmaf(xv, w.z, acc[i * 4 + 2]);
        acc[i * 4 + 3] = fmaf(xv, w.w, acc[i * 4 + 3]);
      }
    }
    float* o = out_feat + (size_t)bs * 128 + c1;
#pragma unroll
    for (int j = 0; j < 32; ++j) {
      float v = acc[j];
#pragma unroll
      for (int off = 32; off; off >>= 1) v = fmaxf(v, __shfl_xor(v, off));
      v = fmaxf(v, 0.0f);  // relu commutes with max
      if (p == 0) o[j] = v;
    }
  }
}

extern "C" void kernel_launch(void* const* d_in, const int* in_sizes, int n_in,
                              void* d_out, int out_size, void* d_ws, size_t ws_size,
                              hipStream_t stream)
{
  (void)in_sizes; (void)n_in; (void)out_size; (void)ws_size;
  const float* pos = (const float*)d_in[0];
  const float* feat = (const float*)d_in[1];
  const float* w1 = (const float*)d_in[2];
  const float* b1 = (const float*)d_in[3];
  const float* w2 = (const float*)d_in[4];
  const float* b2 = (const float*)d_in[5];
  const float* w3 = (const float*)d_in[6];
  const float* b3 = (const float*)d_in[7];

  float* center_out = (float*)d_out;                      // [8,1024,3]
  float* out_feat = (float*)d_out + (size_t)NB * NS * 3;  // [8,1024,128]
  int* gidx = (int*)d_ws;                                 // [8,1024,64]

  fps_kernel<<<NB, 512, 0, stream>>>(pos, center_out);
  ball_kernel<<<(NB * NS) / 4, 256, 0, stream>>>(pos, center_out, gidx);
  mlp_kernel<<<NB * NS, 256, 0, stream>>>(pos, feat, w1, b1, w2, b2, w3, b3,
                                          gidx, center_out, out_feat);
}

// Round 7
// 1402.610 us; speedup vs baseline: 1.9009x; 1.0665x over previous
//
#include <hip/hip_runtime.h>

#define NB 8
#define NN 8192
#define NC 64
#define NS 1024
#define KK 64

typedef unsigned long long u64;

// u64 max-combine with a DPP lane permutation (valid for butterfly max since
// max is commutative+idempotent; patterns pair each lane with a partner that
// already holds its group's max). VALU-pipe only — no LDS traffic.
template <int CTRL>
__device__ __forceinline__ u64 dpp_max_step(u64 k) {
  unsigned lo = (unsigned)k, hi = (unsigned)(k >> 32);
  unsigned plo = (unsigned)__builtin_amdgcn_update_dpp(0, (int)lo, CTRL, 0xF, 0xF, true);
  unsigned phi = (unsigned)__builtin_amdgcn_update_dpp(0, (int)hi, CTRL, 0xF, 0xF, true);
  u64 ok = ((u64)phi << 32) | plo;
  return ok > k ? ok : k;
}
#define DPP_XOR1 0xB1   // quad_perm [1,0,3,2]
#define DPP_XOR2 0x4E   // quad_perm [2,3,0,1]
#define DPP_HM   0x141  // row_half_mirror: i -> 7-i within 8 (pairs quads)
#define DPP_MIR  0x140  // row_mirror: i -> 15-i within 16 (pairs 8-groups)

__device__ __forceinline__ u64 swz16_max(u64 k) {  // lane ^= 16 (ds_swizzle BitMode)
  unsigned lo = (unsigned)k, hi = (unsigned)(k >> 32);
  unsigned plo = (unsigned)__builtin_amdgcn_ds_swizzle((int)lo, 0x401F);
  unsigned phi = (unsigned)__builtin_amdgcn_ds_swizzle((int)hi, 0x401F);
  u64 ok = ((u64)phi << 32) | plo;
  return ok > k ? ok : k;
}

// ---------------------------------------------------------------------------
// Kernel 1: farthest point sampling, float32 exact (bit-exact vs ref; passed
// R1/R4/R6 — selection math unchanged, only transport optimized).
// v3: (a) LDS mirror of all 8192 points -> winner-coords via uniform
// ds_read_b128 (~120cyc) instead of dependent global L2 load (~300-500cyc);
// (b) centers buffered in LDS, cooperative writeout at end (no per-iter
// global store + vmcnt drain at barrier); (c) per-thread argmax as a
// pairwise u64-key tree (chain depth 4 vs 16, same exact semantics).
// ---------------------------------------------------------------------------
__global__ __launch_bounds__(512) void fps_kernel(
    const float* __restrict__ pos, float* __restrict__ center_out)
{
#pragma clang fp contract(off)
  const int b = blockIdx.x;
  const int t = threadIdx.x;
  const int lane = t & 63;
  const int wid = t >> 6;            // 8 waves
  const float* posb = pos + (size_t)b * (NN * 3);

  __shared__ float pmir[NN * 4];     // 128 KB point mirror, [p*4 + {0,1,2}]
  __shared__ float cent[NS * 3];     // 12 KB center buffer
  __shared__ u64 red[2][8];

  float px[16], py[16], pz[16], dist[16];
#pragma unroll
  for (int k = 0; k < 16; ++k) {
    int p = t + (k << 9);
    float x = posb[p * 3 + 0];
    float y = posb[p * 3 + 1];
    float z = posb[p * 3 + 2];
    px[k] = x; py[k] = y; pz[k] = z;
    dist[k] = 1e10f;
    *(float4*)&pmir[p * 4] = make_float4(x, y, z, 0.0f);
  }
  float cx = posb[0], cy = posb[1], cz = posb[2];  // far_0 = 0

  for (int it = 0; it < NS; ++it) {
    if (t == 0) {
      cent[it * 3 + 0] = cx; cent[it * 3 + 1] = cy; cent[it * 3 + 2] = cz;
    }

    // distances: independent per k, issue-bound. contract(off): np op order.
    float nd[16];
#pragma unroll
    for (int k = 0; k < 16; ++k) {
      float dx = px[k] - cx;
      float dy = py[k] - cy;
      float dz = pz[k] - cz;
      float d = ((dx * dx) + (dy * dy)) + (dz * dz);
      float m = fminf(dist[k], d);
      dist[k] = m;
      nd[k] = m;
    }

    // per-thread argmax: u64 keys (dist_bits<<32)|(8191-idx), pairwise tree.
    // max = farthest; equal dist -> larger (8191-idx) = smaller index, exact
    // first-occurrence regardless of combine order.
    u64 key[16];
#pragma unroll
    for (int k = 0; k < 16; ++k) {
      key[k] = ((u64)__float_as_uint(nd[k]) << 32)
             | (unsigned)(8191 - (t + (k << 9)));
    }
#pragma unroll
    for (int s = 8; s; s >>= 1) {
#pragma unroll
      for (int k = 0; k < 8; ++k) {
        if (k < s) { if (key[k + s] > key[k]) key[k] = key[k + s]; }
      }
    }
    u64 kk = key[0];

    // wave butterfly (all lanes end with wave max)
    kk = dpp_max_step<DPP_XOR1>(kk);
    kk = dpp_max_step<DPP_XOR2>(kk);
    kk = dpp_max_step<DPP_HM>(kk);
    kk = dpp_max_step<DPP_MIR>(kk);
    kk = swz16_max(kk);
    { u64 ok = __shfl_xor(kk, 32); if (ok > kk) kk = ok; }

    if (lane == 0) red[it & 1][wid] = kk;
    __syncthreads();  // parity dbuf: red[p] rewritten 2 iters later, post-barrier

    u64 kw = red[it & 1][lane & 7];  // 8 entries, replicated -> broadcast reads
    kw = dpp_max_step<DPP_XOR1>(kw);
    kw = dpp_max_step<DPP_XOR2>(kw);
    kw = dpp_max_step<DPP_HM>(kw);
    int win = 8191 - (int)(unsigned)kw;

    // winner coords: uniform-address LDS broadcast read
    float4 wp = *(const float4*)&pmir[win * 4];
    cx = wp.x; cy = wp.y; cz = wp.z;
  }

  __syncthreads();
  // cooperative center writeout: 1024*3 floats, coalesced
  float* co = center_out + (size_t)b * NS * 3;
  for (int i = t; i < NS * 3; i += 512) co[i] = cent[i];
}

// ---------------------------------------------------------------------------
// Kernel 2: radius ball query, float64 decision boundary (H_B, verified R4).
// One wave per (b,s); ballot-compaction in index order.
// ---------------------------------------------------------------------------
__global__ __launch_bounds__(256) void ball_kernel(
    const float* __restrict__ pos, const float* __restrict__ center_out,
    int* __restrict__ gidx)
{
#pragma clang fp contract(off)
  const double R2D = 0.2 * 0.2;
  int sw = ((blockIdx.x & 7) << 8) | (blockIdx.x >> 3);  // XCD swizzle
  int gw = (sw << 2) | ((int)threadIdx.x >> 6);
  int lane = threadIdx.x & 63;
  int b = gw >> 10;
  int s = gw & 1023;
  const float* posb = pos + (size_t)b * (NN * 3);
  const float* c = center_out + ((size_t)b * NS + s) * 3;
  double cx = (double)c[0], cy = (double)c[1], cz = (double)c[2];
  double cs = ((cx * cx) + (cy * cy)) + (cz * cz);
  int* out = gidx + ((size_t)b * NS + s) * KK;

  int count = 0;
  int first = -1;
  for (int base = 0; base < NN; base += 64) {
    if (count >= KK) break;
    int p = base + lane;
    double x = (double)posb[p * 3 + 0];
    double y = (double)posb[p * 3 + 1];
    double z = (double)posb[p * 3 + 2];
    double ps = ((x * x) + (y * y)) + (z * z);
    double dt = ((cx * x) + (cy * y)) + (cz * z);
    double sqr = (cs + ps) - (2.0 * dt);
    bool inr = !(sqr > R2D);
    u64 m = __ballot(inr);
    if (first < 0 && m) first = base + __builtin_ctzll(m);
    int pre = __popcll(m & ((1ull << lane) - 1ull));
    int slot = count + pre;
    if (inr && slot < KK) out[slot] = p;
    count += (int)__popcll(m);
  }
  if (count < KK) {
    for (int s2 = count + lane; s2 < KK; s2 += 64) out[s2] = first;
  }
}

// ---------------------------------------------------------------------------
// Kernel 3: gather + 3-layer MLP + max-pool (f32). One block per (b,s).
// readfirstlane(q) -> wave-uniform weight addressing (s_load path).
// ---------------------------------------------------------------------------
__global__ __launch_bounds__(256) void mlp_kernel(
    const float* __restrict__ pos, const float* __restrict__ feat,
    const float* __restrict__ w1, const float* __restrict__ b1,
    const float* __restrict__ w2, const float* __restrict__ b2,
    const float* __restrict__ w3, const float* __restrict__ b3,
    const int* __restrict__ gidx, const float* __restrict__ center_out,
    float* __restrict__ out_feat)
{
  __shared__ float Xs[64][67];
  __shared__ float H1s[64][65];
  __shared__ float H2s[64][65];

  int bid = blockIdx.x;
  int bs = ((bid & 7) << 10) | (bid >> 3);  // XCD swizzle: batch per XCD
  int b = bs >> 10;
  int t = threadIdx.x;
  int p = t & 63;
  int q = __builtin_amdgcn_readfirstlane(t >> 6);  // wave-uniform -> SGPR

  int g = gidx[(size_t)bs * KK + p];
  const float* fp = feat + ((size_t)b * NN + g) * NC;
#pragma unroll
  for (int i = 0; i < 4; ++i) {
    float4 v = *(const float4*)(fp + q * 16 + i * 4);
    Xs[p][3 + q * 16 + i * 4 + 0] = v.x;
    Xs[p][3 + q * 16 + i * 4 + 1] = v.y;
    Xs[p][3 + q * 16 + i * 4 + 2] = v.z;
    Xs[p][3 + q * 16 + i * 4 + 3] = v.w;
  }
  if (q == 0) {
    const float* c = center_out + (size_t)bs * 3;
    const float* pp = pos + ((size_t)b * NN + g) * 3;
    Xs[p][0] = pp[0] - c[0];
    Xs[p][1] = pp[1] - c[1];
    Xs[p][2] = pp[2] - c[2];
  }
  __syncthreads();

  // ---- layer 1: [64,67] @ [67,64] ----
  {
    int c0 = q * 16;
    float acc[16];
#pragma unroll
    for (int j = 0; j < 16; ++j) acc[j] = b1[c0 + j];
#pragma unroll 4
    for (int k = 0; k < 67; ++k) {
      float xv = Xs[p][k];
      const float4* wr = (const float4*)(w1 + (size_t)k * 64 + c0);
      float4 wa = wr[0], wb = wr[1], wc = wr[2], wd = wr[3];
      acc[0] = fmaf(xv, wa.x, acc[0]);   acc[1] = fmaf(xv, wa.y, acc[1]);
      acc[2] = fmaf(xv, wa.z, acc[2]);   acc[3] = fmaf(xv, wa.w, acc[3]);
      acc[4] = fmaf(xv, wb.x, acc[4]);   acc[5] = fmaf(xv, wb.y, acc[5]);
      acc[6] = fmaf(xv, wb.z, acc[6]);   acc[7] = fmaf(xv, wb.w, acc[7]);
      acc[8] = fmaf(xv, wc.x, acc[8]);   acc[9] = fmaf(xv, wc.y, acc[9]);
      acc[10] = fmaf(xv, wc.z, acc[10]); acc[11] = fmaf(xv, wc.w, acc[11]);
      acc[12] = fmaf(xv, wd.x, acc[12]); acc[13] = fmaf(xv, wd.y, acc[13]);
      acc[14] = fmaf(xv, wd.z, acc[14]); acc[15] = fmaf(xv, wd.w, acc[15]);
    }
#pragma unroll
    for (int j = 0; j < 16; ++j) H1s[p][c0 + j] = fmaxf(acc[j], 0.0f);
  }
  __syncthreads();

  // ---- layer 2: [64,64] @ [64,64] ----
  {
    int c0 = q * 16;
    float acc[16];
#pragma unroll
    for (int j = 0; j < 16; ++j) acc[j] = b2[c0 + j];
#pragma unroll 4
    for (int k = 0; k < 64; ++k) {
      float xv = H1s[p][k];
      const float4* wr = (const float4*)(w2 + (size_t)k * 64 + c0);
      float4 wa = wr[0], wb = wr[1], wc = wr[2], wd = wr[3];
      acc[0] = fmaf(xv, wa.x, acc[0]);   acc[1] = fmaf(xv, wa.y, acc[1]);
      acc[2] = fmaf(xv, wa.z, acc[2]);   acc[3] = fmaf(xv, wa.w, acc[3]);
      acc[4] = fmaf(xv, wb.x, acc[4]);   acc[5] = fmaf(xv, wb.y, acc[5]);
      acc[6] = fmaf(xv, wb.z, acc[6]);   acc[7] = fmaf(xv, wb.w, acc[7]);
      acc[8] = fmaf(xv, wc.x, acc[8]);   acc[9] = fmaf(xv, wc.y, acc[9]);
      acc[10] = fmaf(xv, wc.z, acc[10]); acc[11] = fmaf(xv, wc.w, acc[11]);
      acc[12] = fmaf(xv, wd.x, acc[12]); acc[13] = fmaf(xv, wd.y, acc[13]);
      acc[14] = fmaf(xv, wd.z, acc[14]); acc[15] = fmaf(xv, wd.w, acc[15]);
    }
#pragma unroll
    for (int j = 0; j < 16; ++j) H2s[p][c0 + j] = fmaxf(acc[j], 0.0f);
  }
  __syncthreads();

  // ---- layer 3: [64,64] @ [64,128], then max over the 64 points ----
  {
    int c1 = q * 32;
    float acc[32];
#pragma unroll
    for (int j = 0; j < 32; ++j) acc[j] = b3[c1 + j];
#pragma unroll 2
    for (int k = 0; k < 64; ++k) {
      float xv = H2s[p][k];
      const float4* wr = (const float4*)(w3 + (size_t)k * 128 + c1);
#pragma unroll
      for (int i = 0; i < 8; ++i) {
        float4 w = wr[i];
        acc[i * 4 + 0] = fmaf(xv, w.x, acc[i * 4 + 0]);
        acc[i * 4 + 1] = fmaf(xv, w.y, acc[i * 4 + 1]);
        acc[i * 4 + 2] = fmaf(xv, w.z, acc[i * 4 + 2]);
        acc[i * 4 + 3] = fmaf(xv, w.w, acc[i * 4 + 3]);
      }
    }
    float* o = out_feat + (size_t)bs * 128 + c1;
#pragma unroll
    for (int j = 0; j < 32; ++j) {
      float v = acc[j];
#pragma unroll
      for (int off = 32; off; off >>= 1) v = fmaxf(v, __shfl_xor(v, off));
      v = fmaxf(v, 0.0f);  // relu commutes with max
      if (p == 0) o[j] = v;
    }
  }
}

extern "C" void kernel_launch(void* const* d_in, const int* in_sizes, int n_in,
                              void* d_out, int out_size, void* d_ws, size_t ws_size,
                              hipStream_t stream)
{
  (void)in_sizes; (void)n_in; (void)out_size; (void)ws_size;
  const float* pos = (const float*)d_in[0];
  const float* feat = (const float*)d_in[1];
  const float* w1 = (const float*)d_in[2];
  const float* b1 = (const float*)d_in[3];
  const float* w2 = (const float*)d_in[4];
  const float* b2 = (const float*)d_in[5];
  const float* w3 = (const float*)d_in[6];
  const float* b3 = (const float*)d_in[7];

  float* center_out = (float*)d_out;                      // [8,1024,3]
  float* out_feat = (float*)d_out + (size_t)NB * NS * 3;  // [8,1024,128]
  int* gidx = (int*)d_ws;                                 // [8,1024,64]

  fps_kernel<<<NB, 512, 0, stream>>>(pos, center_out);
  ball_kernel<<<(NB * NS) / 4, 256, 0, stream>>>(pos, center_out, gidx);
  mlp_kernel<<<NB * NS, 256, 0, stream>>>(pos, feat, w1, b1, w2, b2, w3, b3,
                                          gidx, center_out, out_feat);
}

// Round 9
// 1356.126 us; speedup vs baseline: 1.9661x; 1.0343x over previous
//
#include <hip/hip_runtime.h>

#define NB 8
#define NN 8192
#define NC 64
#define NS 1024
#define KK 64

typedef unsigned long long u64;
typedef float f32x2 __attribute__((ext_vector_type(2)));

// u64 max-combine with a DPP lane permutation (valid for butterfly max since
// max is commutative+idempotent). VALU-pipe only — no LDS traffic.
template <int CTRL>
__device__ __forceinline__ u64 dpp_max_step(u64 k) {
  unsigned lo = (unsigned)k, hi = (unsigned)(k >> 32);
  unsigned plo = (unsigned)__builtin_amdgcn_update_dpp(0, (int)lo, CTRL, 0xF, 0xF, true);
  unsigned phi = (unsigned)__builtin_amdgcn_update_dpp(0, (int)hi, CTRL, 0xF, 0xF, true);
  u64 ok = ((u64)phi << 32) | plo;
  return ok > k ? ok : k;
}
#define DPP_XOR1 0xB1   // quad_perm [1,0,3,2]
#define DPP_XOR2 0x4E   // quad_perm [2,3,0,1]
#define DPP_HM   0x141  // row_half_mirror
#define DPP_MIR  0x140  // row_mirror

__device__ __forceinline__ u64 swz16_max(u64 k) {  // lane ^= 16 (BitMode)
  unsigned lo = (unsigned)k, hi = (unsigned)(k >> 32);
  unsigned plo = (unsigned)__builtin_amdgcn_ds_swizzle((int)lo, 0x401F);
  unsigned phi = (unsigned)__builtin_amdgcn_ds_swizzle((int)hi, 0x401F);
  u64 ok = ((u64)phi << 32) | plo;
  return ok > k ? ok : k;
}

// ---------------------------------------------------------------------------
// Kernel 1: FPS, float32 exact (bit-exact vs ref; passed R1/R4/R6/R7).
// v4: dist pipeline on packed f32 pairs (v_pk_sub/mul/add — 2 pts/inst,
// IEEE-identical per element, contract(off) still enforced) — cuts the
// dominant VALU bucket 144->~80 inst/wave/iter. Selection semantics
// unchanged: same u64 keys, same tree/butterfly/stage2.
// ---------------------------------------------------------------------------
__global__ __launch_bounds__(512) void fps_kernel(
    const float* __restrict__ pos, float* __restrict__ center_out)
{
#pragma clang fp contract(off)
  const int b = blockIdx.x;
  const int t = threadIdx.x;
  const int lane = t & 63;
  const int wid = t >> 6;            // 8 waves
  const float* posb = pos + (size_t)b * (NN * 3);

  __shared__ float pmir[NN * 4];     // 128 KB point mirror
  __shared__ float cent[NS * 3];     // 12 KB center buffer
  __shared__ u64 red[2][8];

  // pair j holds points p0 = t + (2j<<9), p1 = p0 + 512 (k=2j, 2j+1)
  f32x2 X[8], Y[8], Z[8], D[8];
  unsigned lokey[16];
#pragma unroll
  for (int j = 0; j < 8; ++j) {
    int p0 = t + ((2 * j) << 9);
    int p1 = p0 + 512;
    float x0 = posb[p0 * 3 + 0], y0 = posb[p0 * 3 + 1], z0 = posb[p0 * 3 + 2];
    float x1 = posb[p1 * 3 + 0], y1 = posb[p1 * 3 + 1], z1 = posb[p1 * 3 + 2];
    X[j][0] = x0; X[j][1] = x1;
    Y[j][0] = y0; Y[j][1] = y1;
    Z[j][0] = z0; Z[j][1] = z1;
    D[j][0] = 1e10f; D[j][1] = 1e10f;
    *(float4*)&pmir[p0 * 4] = make_float4(x0, y0, z0, 0.0f);
    *(float4*)&pmir[p1 * 4] = make_float4(x1, y1, z1, 0.0f);
    lokey[2 * j]     = (unsigned)(8191 - p0);
    lokey[2 * j + 1] = (unsigned)(8191 - p1);
  }
  float cx = posb[0], cy = posb[1], cz = posb[2];  // far_0 = 0

  for (int it = 0; it < NS; ++it) {
    if (t == 0) {
      cent[it * 3 + 0] = cx; cent[it * 3 + 1] = cy; cent[it * 3 + 2] = cz;
    }

    // packed distance update: <2 x float> sub/mul/add -> v_pk_* (exact IEEE
    // per element, np op order preserved, no contraction)
    f32x2 c2x, c2y, c2z;
    c2x[0] = cx; c2x[1] = cx;
    c2y[0] = cy; c2y[1] = cy;
    c2z[0] = cz; c2z[1] = cz;
    u64 key[16];
#pragma unroll
    for (int j = 0; j < 8; ++j) {
      f32x2 dx = X[j] - c2x;
      f32x2 dy = Y[j] - c2y;
      f32x2 dz = Z[j] - c2z;
      f32x2 d = ((dx * dx) + (dy * dy)) + (dz * dz);
      float m0 = fminf(D[j][0], d[0]);   // scalar min: halves are plain VGPRs
      float m1 = fminf(D[j][1], d[1]);
      D[j][0] = m0; D[j][1] = m1;
      key[2 * j]     = ((u64)__float_as_uint(m0) << 32) | lokey[2 * j];
      key[2 * j + 1] = ((u64)__float_as_uint(m1) << 32) | lokey[2 * j + 1];
    }

    // in-thread pairwise tree (exact first-occurrence via key encoding)
#pragma unroll
    for (int s = 8; s; s >>= 1) {
#pragma unroll
      for (int k = 0; k < 8; ++k) {
        if (k < s) { if (key[k + s] > key[k]) key[k] = key[k + s]; }
      }
    }
    u64 kk = key[0];

    // wave butterfly (all lanes end with wave max)
    kk = dpp_max_step<DPP_XOR1>(kk);
    kk = dpp_max_step<DPP_XOR2>(kk);
    kk = dpp_max_step<DPP_HM>(kk);
    kk = dpp_max_step<DPP_MIR>(kk);
    kk = swz16_max(kk);
    { u64 ok = __shfl_xor(kk, 32); if (ok > kk) kk = ok; }

    if (lane == 0) red[it & 1][wid] = kk;
    __syncthreads();  // parity dbuf: red[p] rewritten 2 iters later

    u64 kw = red[it & 1][lane & 7];
    kw = dpp_max_step<DPP_XOR1>(kw);
    kw = dpp_max_step<DPP_XOR2>(kw);
    kw = dpp_max_step<DPP_HM>(kw);
    int win = 8191 - (int)(unsigned)kw;

    // winner coords: uniform-address LDS broadcast read
    float4 wp = *(const float4*)&pmir[win * 4];
    cx = wp.x; cy = wp.y; cz = wp.z;
  }

  __syncthreads();
  float* co = center_out + (size_t)b * NS * 3;
  for (int i = t; i < NS * 3; i += 512) co[i] = cent[i];
}

// ---------------------------------------------------------------------------
// Kernel 2: radius ball query, float64 decision boundary (H_B, verified R4).
// One wave per (b,s); ballot-compaction in index order. UNCHANGED.
// ---------------------------------------------------------------------------
__global__ __launch_bounds__(256) void ball_kernel(
    const float* __restrict__ pos, const float* __restrict__ center_out,
    int* __restrict__ gidx)
{
#pragma clang fp contract(off)
  const double R2D = 0.2 * 0.2;
  int sw = ((blockIdx.x & 7) << 8) | (blockIdx.x >> 3);  // XCD swizzle
  int gw = (sw << 2) | ((int)threadIdx.x >> 6);
  int lane = threadIdx.x & 63;
  int b = gw >> 10;
  int s = gw & 1023;
  const float* posb = pos + (size_t)b * (NN * 3);
  const float* c = center_out + ((size_t)b * NS + s) * 3;
  double cx = (double)c[0], cy = (double)c[1], cz = (double)c[2];
  double cs = ((cx * cx) + (cy * cy)) + (cz * cz);
  int* out = gidx + ((size_t)b * NS + s) * KK;

  int count = 0;
  int first = -1;
  for (int base = 0; base < NN; base += 64) {
    if (count >= KK) break;
    int p = base + lane;
    double x = (double)posb[p * 3 + 0];
    double y = (double)posb[p * 3 + 1];
    double z = (double)posb[p * 3 + 2];
    double ps = ((x * x) + (y * y)) + (z * z);
    double dt = ((cx * x) + (cy * y)) + (cz * z);
    double sqr = (cs + ps) - (2.0 * dt);
    bool inr = !(sqr > R2D);
    u64 m = __ballot(inr);
    if (first < 0 && m) first = base + __builtin_ctzll(m);
    int pre = __popcll(m & ((1ull << lane) - 1ull));
    int slot = count + pre;
    if (inr && slot < KK) out[slot] = p;
    count += (int)__popcll(m);
  }
  if (count < KK) {
    for (int s2 = count + lane; s2 < KK; s2 += 64) out[s2] = first;
  }
}

// ---------------------------------------------------------------------------
// Kernel 3: gather + 3-layer MLP + max-pool (f32). One block per (b,s).
// UNCHANGED.
// ---------------------------------------------------------------------------
__global__ __launch_bounds__(256) void mlp_kernel(
    const float* __restrict__ pos, const float* __restrict__ feat,
    const float* __restrict__ w1, const float* __restrict__ b1,
    const float* __restrict__ w2, const float* __restrict__ b2,
    const float* __restrict__ w3, const float* __restrict__ b3,
    const int* __restrict__ gidx, const float* __restrict__ center_out,
    float* __restrict__ out_feat)
{
  __shared__ float Xs[64][67];
  __shared__ float H1s[64][65];
  __shared__ float H2s[64][65];

  int bid = blockIdx.x;
  int bs = ((bid & 7) << 10) | (bid >> 3);  // XCD swizzle: batch per XCD
  int b = bs >> 10;
  int t = threadIdx.x;
  int p = t & 63;
  int q = __builtin_amdgcn_readfirstlane(t >> 6);  // wave-uniform -> SGPR

  int g = gidx[(size_t)bs * KK + p];
  const float* fp = feat + ((size_t)b * NN + g) * NC;
#pragma unroll
  for (int i = 0; i < 4; ++i) {
    float4 v = *(const float4*)(fp + q * 16 + i * 4);
    Xs[p][3 + q * 16 + i * 4 + 0] = v.x;
    Xs[p][3 + q * 16 + i * 4 + 1] = v.y;
    Xs[p][3 + q * 16 + i * 4 + 2] = v.z;
    Xs[p][3 + q * 16 + i * 4 + 3] = v.w;
  }
  if (q == 0) {
    const float* c = center_out + (size_t)bs * 3;
    const float* pp = pos + ((size_t)b * NN + g) * 3;
    Xs[p][0] = pp[0] - c[0];
    Xs[p][1] = pp[1] - c[1];
    Xs[p][2] = pp[2] - c[2];
  }
  __syncthreads();

  // ---- layer 1: [64,67] @ [67,64] ----
  {
    int c0 = q * 16;
    float acc[16];
#pragma unroll
    for (int j = 0; j < 16; ++j) acc[j] = b1[c0 + j];
#pragma unroll 4
    for (int k = 0; k < 67; ++k) {
      float xv = Xs[p][k];
      const float4* wr = (const float4*)(w1 + (size_t)k * 64 + c0);
      float4 wa = wr[0], wb = wr[1], wc = wr[2], wd = wr[3];
      acc[0] = fmaf(xv, wa.x, acc[0]);   acc[1] = fmaf(xv, wa.y, acc[1]);
      acc[2] = fmaf(xv, wa.z, acc[2]);   acc[3] = fmaf(xv, wa.w, acc[3]);
      acc[4] = fmaf(xv, wb.x, acc[4]);   acc[5] = fmaf(xv, wb.y, acc[5]);
      acc[6] = fmaf(xv, wb.z, acc[6]);   acc[7] = fmaf(xv, wb.w, acc[7]);
      acc[8] = fmaf(xv, wc.x, acc[8]);   acc[9] = fmaf(xv, wc.y, acc[9]);
      acc[10] = fmaf(xv, wc.z, acc[10]); acc[11] = fmaf(xv, wc.w, acc[11]);
      acc[12] = fmaf(xv, wd.x, acc[12]); acc[13] = fmaf(xv, wd.y, acc[13]);
      acc[14] = fmaf(xv, wd.z, acc[14]); acc[15] = fmaf(xv, wd.w, acc[15]);
    }
#pragma unroll
    for (int j = 0; j < 16; ++j) H1s[p][c0 + j] = fmaxf(acc[j], 0.0f);
  }
  __syncthreads();

  // ---- layer 2: [64,64] @ [64,64] ----
  {
    int c0 = q * 16;
    float acc[16];
#pragma unroll
    for (int j = 0; j < 16; ++j) acc[j] = b2[c0 + j];
#pragma unroll 4
    for (int k = 0; k < 64; ++k) {
      float xv = H1s[p][k];
      const float4* wr = (const float4*)(w2 + (size_t)k * 64 + c0);
      float4 wa = wr[0], wb = wr[1], wc = wr[2], wd = wr[3];
      acc[0] = fmaf(xv, wa.x, acc[0]);   acc[1] = fmaf(xv, wa.y, acc[1]);
      acc[2] = fmaf(xv, wa.z, acc[2]);   acc[3] = fmaf(xv, wa.w, acc[3]);
      acc[4] = fmaf(xv, wb.x, acc[4]);   acc[5] = fmaf(xv, wb.y, acc[5]);
      acc[6] = fmaf(xv, wb.z, acc[6]);   acc[7] = fmaf(xv, wb.w, acc[7]);
      acc[8] = fmaf(xv, wc.x, acc[8]);   acc[9] = fmaf(xv, wc.y, acc[9]);
      acc[10] = fmaf(xv, wc.z, acc[10]); acc[11] = fmaf(xv, wc.w, acc[11]);
      acc[12] = fmaf(xv, wd.x, acc[12]); acc[13] = fmaf(xv, wd.y, acc[13]);
      acc[14] = fmaf(xv, wd.z, acc[14]); acc[15] = fmaf(xv, wd.w, acc[15]);
    }
#pragma unroll
    for (int j = 0; j < 16; ++j) H2s[p][c0 + j] = fmaxf(acc[j], 0.0f);
  }
  __syncthreads();

  // ---- layer 3: [64,64] @ [64,128], then max over the 64 points ----
  {
    int c1 = q * 32;
    float acc[32];
#pragma unroll
    for (int j = 0; j < 32; ++j) acc[j] = b3[c1 + j];
#pragma unroll 2
    for (int k = 0; k < 64; ++k) {
      float xv = H2s[p][k];
      const float4* wr = (const float4*)(w3 + (size_t)k * 128 + c1);
#pragma unroll
      for (int i = 0; i < 8; ++i) {
        float4 w = wr[i];
        acc[i * 4 + 0] = fmaf(xv, w.x, acc[i * 4 + 0]);
        acc[i * 4 + 1] = fmaf(xv, w.y, acc[i * 4 + 1]);
        acc[i * 4 + 2] = fmaf(xv, w.z, acc[i * 4 + 2]);
        acc[i * 4 + 3] = fmaf(xv, w.w, acc[i * 4 + 3]);
      }
    }
    float* o = out_feat + (size_t)bs * 128 + c1;
#pragma unroll
    for (int j = 0; j < 32; ++j) {
      float v = acc[j];
#pragma unroll
      for (int off = 32; off; off >>= 1) v = fmaxf(v, __shfl_xor(v, off));
      v = fmaxf(v, 0.0f);  // relu commutes with max
      if (p == 0) o[j] = v;
    }
  }
}

extern "C" void kernel_launch(void* const* d_in, const int* in_sizes, int n_in,
                              void* d_out, int out_size, void* d_ws, size_t ws_size,
                              hipStream_t stream)
{
  (void)in_sizes; (void)n_in; (void)out_size; (void)ws_size;
  const float* pos = (const float*)d_in[0];
  const float* feat = (const float*)d_in[1];
  const float* w1 = (const float*)d_in[2];
  const float* b1 = (const float*)d_in[3];
  const float* w2 = (const float*)d_in[4];
  const float* b2 = (const float*)d_in[5];
  const float* w3 = (const float*)d_in[6];
  const float* b3 = (const float*)d_in[7];

  float* center_out = (float*)d_out;                      // [8,1024,3]
  float* out_feat = (float*)d_out + (size_t)NB * NS * 3;  // [8,1024,128]
  int* gidx = (int*)d_ws;                                 // [8,1024,64]

  fps_kernel<<<NB, 512, 0, stream>>>(pos, center_out);
  ball_kernel<<<(NB * NS) / 4, 256, 0, stream>>>(pos, center_out, gidx);
  mlp_kernel<<<NB * NS, 256, 0, stream>>>(pos, feat, w1, b1, w2, b2, w3, b3,
                                          gidx, center_out, out_feat);
}

// Round 11
// 1270.783 us; speedup vs baseline: 2.0981x; 1.0672x over previous
//
#include <hip/hip_runtime.h>

#define NB 8
#define NN 8192
#define NC 64
#define NS 1024
#define KK 64

typedef unsigned long long u64;
typedef float f32x2 __attribute__((ext_vector_type(2)));

// f64 max-combine with a DPP lane permutation (2 v_mov_dpp + 1 v_max_f64).
// Keys are nonneg integer-valued doubles; bound_ctrl=true feeds 0.0 to
// pattern-invalid lanes, harmless under max.
template <int CTRL>
__device__ __forceinline__ double dpp_max_f64(double v) {
  u64 b = (u64)__double_as_longlong(v);
  unsigned lo = (unsigned)b, hi = (unsigned)(b >> 32);
  unsigned plo = (unsigned)__builtin_amdgcn_update_dpp(0, (int)lo, CTRL, 0xF, 0xF, true);
  unsigned phi = (unsigned)__builtin_amdgcn_update_dpp(0, (int)hi, CTRL, 0xF, 0xF, true);
  double o = __longlong_as_double((long long)(((u64)phi << 32) | plo));
  return fmax(v, o);
}
#define DPP_XOR1 0xB1   // quad_perm [1,0,3,2]
#define DPP_XOR2 0x4E   // quad_perm [2,3,0,1]
#define DPP_HM   0x141  // row_half_mirror (xor4-equivalent after quad reduce)
#define DPP_MIR  0x140  // row_mirror     (xor8-equivalent after 8-reduce)
#define DPP_BC15 0x142  // row_bcast15: row N+1 receives lane 15 of row N
#define DPP_BC31 0x143  // row_bcast31: rows 2,3 receive lane 31

// ---------------------------------------------------------------------------
// Kernel 1: FPS, float32 exact (bit-exact vs ref; passed R1/R4/R6/R7/R9).
// v5: selection key re-encoded as EXACT integer-valued f64:
//   key = (double)dist_bits * 8192 + (8191 - idx)   (<= 2^45, exact fma)
// f64 max == u64 lexicographic compare -> selection order provably identical.
// Wave reduction = pure-DPP ladder (4 row steps + bcast15 + bcast31), lane 63
// owns the wave max; stage-2 = 3 DPP-f64 steps. No ds_swizzle/bpermute on the
// serial chain. Dist math unchanged (packed f32, contract(off), np order).
// ---------------------------------------------------------------------------
__global__ __launch_bounds__(512) void fps_kernel(
    const float* __restrict__ pos, float* __restrict__ center_out)
{
#pragma clang fp contract(off)
  const int b = blockIdx.x;
  const int t = threadIdx.x;
  const int lane = t & 63;
  const int wid = t >> 6;            // 8 waves
  const float* posb = pos + (size_t)b * (NN * 3);

  __shared__ float pmir[NN * 4];     // 128 KB point mirror
  __shared__ float cent[NS * 3];     // 12 KB center buffer
  __shared__ double red[2][8];

  // pair j holds points p0 = t + (2j<<9), p1 = p0 + 512
  f32x2 X[8], Y[8], Z[8], D[8];
  double lokeyd[16];
#pragma unroll
  for (int j = 0; j < 8; ++j) {
    int p0 = t + ((2 * j) << 9);
    int p1 = p0 + 512;
    float x0 = posb[p0 * 3 + 0], y0 = posb[p0 * 3 + 1], z0 = posb[p0 * 3 + 2];
    float x1 = posb[p1 * 3 + 0], y1 = posb[p1 * 3 + 1], z1 = posb[p1 * 3 + 2];
    X[j][0] = x0; X[j][1] = x1;
    Y[j][0] = y0; Y[j][1] = y1;
    Z[j][0] = z0; Z[j][1] = z1;
    D[j][0] = 1e10f; D[j][1] = 1e10f;
    *(float4*)&pmir[p0 * 4] = make_float4(x0, y0, z0, 0.0f);
    *(float4*)&pmir[p1 * 4] = make_float4(x1, y1, z1, 0.0f);
    lokeyd[2 * j]     = (double)(8191 - p0);
    lokeyd[2 * j + 1] = (double)(8191 - p1);
  }
  float cx = posb[0], cy = posb[1], cz = posb[2];  // far_0 = 0

  for (int it = 0; it < NS; ++it) {
    if (t == 0) {
      cent[it * 3 + 0] = cx; cent[it * 3 + 1] = cy; cent[it * 3 + 2] = cz;
    }

    // packed distance update (v_pk_*, IEEE per element, np op order)
    f32x2 c2x, c2y, c2z;
    c2x[0] = cx; c2x[1] = cx;
    c2y[0] = cy; c2y[1] = cy;
    c2z[0] = cz; c2z[1] = cz;
    double key[16];
#pragma unroll
    for (int j = 0; j < 8; ++j) {
      f32x2 dx = X[j] - c2x;
      f32x2 dy = Y[j] - c2y;
      f32x2 dz = Z[j] - c2z;
      f32x2 d = ((dx * dx) + (dy * dy)) + (dz * dz);
      float m0 = fminf(D[j][0], d[0]);
      float m1 = fminf(D[j][1], d[1]);
      D[j][0] = m0; D[j][1] = m1;
      // exact: dist_bits*8192 + (8191-idx) <= 2^45 < 2^53
      key[2 * j]     = fma((double)__float_as_uint(m0), 8192.0, lokeyd[2 * j]);
      key[2 * j + 1] = fma((double)__float_as_uint(m1), 8192.0, lokeyd[2 * j + 1]);
    }

    // in-thread pairwise tree: 15 x v_max_f64 (== u64 lexicographic order)
#pragma unroll
    for (int s = 8; s; s >>= 1) {
#pragma unroll
      for (int k = 0; k < 8; ++k) {
        if (k < s) key[k] = fmax(key[k], key[k + s]);
      }
    }
    double kk = key[0];

    // wave ladder: rows, then bcast merge; lanes 48-63 hold wave max
    kk = dpp_max_f64<DPP_XOR1>(kk);
    kk = dpp_max_f64<DPP_XOR2>(kk);
    kk = dpp_max_f64<DPP_HM>(kk);
    kk = dpp_max_f64<DPP_MIR>(kk);    // each 16-row: row max in all lanes
    kk = dpp_max_f64<DPP_BC15>(kk);   // row1=r0|r1, row2=r1|r2, row3=r2|r3
    kk = dpp_max_f64<DPP_BC31>(kk);   // row3 = total wave max

    if (lane == 63) red[it & 1][wid] = kk;
    __syncthreads();  // parity dbuf: red[p] rewritten 2 iters later

    double kw = red[it & 1][lane & 7];  // 8 entries replicated -> broadcast
    kw = dpp_max_f64<DPP_XOR1>(kw);
    kw = dpp_max_f64<DPP_XOR2>(kw);
    kw = dpp_max_f64<DPP_HM>(kw);       // all lanes: global max key

    // decode (all exact: kw integer-valued, q = dist_bits, rem = 8191-win)
    double q = trunc(kw * (1.0 / 8192.0));
    double rem = fma(q, -8192.0, kw);
    int win = 8191 - (int)rem;

    // winner coords: uniform-address LDS broadcast read
    float4 wp = *(const float4*)&pmir[win * 4];
    cx = wp.x; cy = wp.y; cz = wp.z;
  }

  __syncthreads();
  float* co = center_out + (size_t)b * NS * 3;
  for (int i = t; i < NS * 3; i += 512) co[i] = cent[i];
}

// ---------------------------------------------------------------------------
// Kernel 2: radius ball query, float64 decision boundary (H_B, verified R4).
// One wave per (b,s); ballot-compaction in index order. UNCHANGED.
// ---------------------------------------------------------------------------
__global__ __launch_bounds__(256) void ball_kernel(
    const float* __restrict__ pos, const float* __restrict__ center_out,
    int* __restrict__ gidx)
{
#pragma clang fp contract(off)
  const double R2D = 0.2 * 0.2;
  int sw = ((blockIdx.x & 7) << 8) | (blockIdx.x >> 3);  // XCD swizzle
  int gw = (sw << 2) | ((int)threadIdx.x >> 6);
  int lane = threadIdx.x & 63;
  int b = gw >> 10;
  int s = gw & 1023;
  const float* posb = pos + (size_t)b * (NN * 3);
  const float* c = center_out + ((size_t)b * NS + s) * 3;
  double cx = (double)c[0], cy = (double)c[1], cz = (double)c[2];
  double cs = ((cx * cx) + (cy * cy)) + (cz * cz);
  int* out = gidx + ((size_t)b * NS + s) * KK;

  int count = 0;
  int first = -1;
  for (int base = 0; base < NN; base += 64) {
    if (count >= KK) break;
    int p = base + lane;
    double x = (double)posb[p * 3 + 0];
    double y = (double)posb[p * 3 + 1];
    double z = (double)posb[p * 3 + 2];
    double ps = ((x * x) + (y * y)) + (z * z);
    double dt = ((cx * x) + (cy * y)) + (cz * z);
    double sqr = (cs + ps) - (2.0 * dt);
    bool inr = !(sqr > R2D);
    u64 m = __ballot(inr);
    if (first < 0 && m) first = base + __builtin_ctzll(m);
    int pre = __popcll(m & ((1ull << lane) - 1ull));
    int slot = count + pre;
    if (inr && slot < KK) out[slot] = p;
    count += (int)__popcll(m);
  }
  if (count < KK) {
    for (int s2 = count + lane; s2 < KK; s2 += 64) out[s2] = first;
  }
}

// ---------------------------------------------------------------------------
// Kernel 3: gather + 3-layer MLP + max-pool (f32). One block per (b,s).
// UNCHANGED.
// ---------------------------------------------------------------------------
__global__ __launch_bounds__(256) void mlp_kernel(
    const float* __restrict__ pos, const float* __restrict__ feat,
    const float* __restrict__ w1, const float* __restrict__ b1,
    const float* __restrict__ w2, const float* __restrict__ b2,
    const float* __restrict__ w3, const float* __restrict__ b3,
    const int* __restrict__ gidx, const float* __restrict__ center_out,
    float* __restrict__ out_feat)
{
  __shared__ float Xs[64][67];
  __shared__ float H1s[64][65];
  __shared__ float H2s[64][65];

  int bid = blockIdx.x;
  int bs = ((bid & 7) << 10) | (bid >> 3);  // XCD swizzle: batch per XCD
  int b = bs >> 10;
  int t = threadIdx.x;
  int p = t & 63;
  int q = __builtin_amdgcn_readfirstlane(t >> 6);  // wave-uniform -> SGPR

  int g = gidx[(size_t)bs * KK + p];
  const float* fp = feat + ((size_t)b * NN + g) * NC;
#pragma unroll
  for (int i = 0; i < 4; ++i) {
    float4 v = *(const float4*)(fp + q * 16 + i * 4);
    Xs[p][3 + q * 16 + i * 4 + 0] = v.x;
    Xs[p][3 + q * 16 + i * 4 + 1] = v.y;
    Xs[p][3 + q * 16 + i * 4 + 2] = v.z;
    Xs[p][3 + q * 16 + i * 4 + 3] = v.w;
  }
  if (q == 0) {
    const float* c = center_out + (size_t)bs * 3;
    const float* pp = pos + ((size_t)b * NN + g) * 3;
    Xs[p][0] = pp[0] - c[0];
    Xs[p][1] = pp[1] - c[1];
    Xs[p][2] = pp[2] - c[2];
  }
  __syncthreads();

  // ---- layer 1: [64,67] @ [67,64] ----
  {
    int c0 = q * 16;
    float acc[16];
#pragma unroll
    for (int j = 0; j < 16; ++j) acc[j] = b1[c0 + j];
#pragma unroll 4
    for (int k = 0; k < 67; ++k) {
      float xv = Xs[p][k];
      const float4* wr = (const float4*)(w1 + (size_t)k * 64 + c0);
      float4 wa = wr[0], wb = wr[1], wc = wr[2], wd = wr[3];
      acc[0] = fmaf(xv, wa.x, acc[0]);   acc[1] = fmaf(xv, wa.y, acc[1]);
      acc[2] = fmaf(xv, wa.z, acc[2]);   acc[3] = fmaf(xv, wa.w, acc[3]);
      acc[4] = fmaf(xv, wb.x, acc[4]);   acc[5] = fmaf(xv, wb.y, acc[5]);
      acc[6] = fmaf(xv, wb.z, acc[6]);   acc[7] = fmaf(xv, wb.w, acc[7]);
      acc[8] = fmaf(xv, wc.x, acc[8]);   acc[9] = fmaf(xv, wc.y, acc[9]);
      acc[10] = fmaf(xv, wc.z, acc[10]); acc[11] = fmaf(xv, wc.w, acc[11]);
      acc[12] = fmaf(xv, wd.x, acc[12]); acc[13] = fmaf(xv, wd.y, acc[13]);
      acc[14] = fmaf(xv, wd.z, acc[14]); acc[15] = fmaf(xv, wd.w, acc[15]);
    }
#pragma unroll
    for (int j = 0; j < 16; ++j) H1s[p][c0 + j] = fmaxf(acc[j], 0.0f);
  }
  __syncthreads();

  // ---- layer 2: [64,64] @ [64,64] ----
  {
    int c0 = q * 16;
    float acc[16];
#pragma unroll
    for (int j = 0; j < 16; ++j) acc[j] = b2[c0 + j];
#pragma unroll 4
    for (int k = 0; k < 64; ++k) {
      float xv = H1s[p][k];
      const float4* wr = (const float4*)(w2 + (size_t)k * 64 + c0);
      float4 wa = wr[0], wb = wr[1], wc = wr[2], wd = wr[3];
      acc[0] = fmaf(xv, wa.x, acc[0]);   acc[1] = fmaf(xv, wa.y, acc[1]);
      acc[2] = fmaf(xv, wa.z, acc[2]);   acc[3] = fmaf(xv, wa.w, acc[3]);
      acc[4] = fmaf(xv, wb.x, acc[4]);   acc[5] = fmaf(xv, wb.y, acc[5]);
      acc[6] = fmaf(xv, wb.z, acc[6]);   acc[7] = fmaf(xv, wb.w, acc[7]);
      acc[8] = fmaf(xv, wc.x, acc[8]);   acc[9] = fmaf(xv, wc.y, acc[9]);
      acc[10] = fmaf(xv, wc.z, acc[10]); acc[11] = fmaf(xv, wc.w, acc[11]);
      acc[12] = fmaf(xv, wd.x, acc[12]); acc[13] = fmaf(xv, wd.y, acc[13]);
      acc[14] = fmaf(xv, wd.z, acc[14]); acc[15] = fmaf(xv, wd.w, acc[15]);
    }
#pragma unroll
    for (int j = 0; j < 16; ++j) H2s[p][c0 + j] = fmaxf(acc[j], 0.0f);
  }
  __syncthreads();

  // ---- layer 3: [64,64] @ [64,128], then max over the 64 points ----
  {
    int c1 = q * 32;
    float acc[32];
#pragma unroll
    for (int j = 0; j < 32; ++j) acc[j] = b3[c1 + j];
#pragma unroll 2
    for (int k = 0; k < 64; ++k) {
      float xv = H2s[p][k];
      const float4* wr = (const float4*)(w3 + (size_t)k * 128 + c1);
#pragma unroll
      for (int i = 0; i < 8; ++i) {
        float4 w = wr[i];
        acc[i * 4 + 0] = fmaf(xv, w.x, acc[i * 4 + 0]);
        acc[i * 4 + 1] = fmaf(xv, w.y, acc[i * 4 + 1]);
        acc[i * 4 + 2] = fmaf(xv, w.z, acc[i * 4 + 2]);
        acc[i * 4 + 3] = fmaf(xv, w.w, acc[i * 4 + 3]);
      }
    }
    float* o = out_feat + (size_t)bs * 128 + c1;
#pragma unroll
    for (int j = 0; j < 32; ++j) {
      float v = acc[j];
#pragma unroll
      for (int off = 32; off; off >>= 1) v = fmaxf(v, __shfl_xor(v, off));
      v = fmaxf(v, 0.0f);  // relu commutes with max
      if (p == 0) o[j] = v;
    }
  }
}

extern "C" void kernel_launch(void* const* d_in, const int* in_sizes, int n_in,
                              void* d_out, int out_size, void* d_ws, size_t ws_size,
                              hipStream_t stream)
{
  (void)in_sizes; (void)n_in; (void)out_size; (void)ws_size;
  const float* pos = (const float*)d_in[0];
  const float* feat = (const float*)d_in[1];
  const float* w1 = (const float*)d_in[2];
  const float* b1 = (const float*)d_in[3];
  const float* w2 = (const float*)d_in[4];
  const float* b2 = (const float*)d_in[5];
  const float* w3 = (const float*)d_in[6];
  const float* b3 = (const float*)d_in[7];

  float* center_out = (float*)d_out;                      // [8,1024,3]
  float* out_feat = (float*)d_out + (size_t)NB * NS * 3;  // [8,1024,128]
  int* gidx = (int*)d_ws;                                 // [8,1024,64]

  fps_kernel<<<NB, 512, 0, stream>>>(pos, center_out);
  ball_kernel<<<(NB * NS) / 4, 256, 0, stream>>>(pos, center_out, gidx);
  mlp_kernel<<<NB * NS, 256, 0, stream>>>(pos, feat, w1, b1, w2, b2, w3, b3,
                                          gidx, center_out, out_feat);
}